// Round 1
// baseline (826.307 us; speedup 1.0000x reference)
//
#include <hip/hip_runtime.h>

// LearnableGate: out = [TN*tanh(x0@W0*s0) (128) | (x1@W1*s1)*gate (192) | (x2@W2*s2)*gate (160)]
// N=262144 rows, DIN=DOUT=480 fp32. HBM-bound target ~160us @ 6.3TB/s.

typedef float  f32x4  __attribute__((ext_vector_type(4)));
typedef __bf16 bf16x8 __attribute__((ext_vector_type(8)));
typedef float  f4a4   __attribute__((ext_vector_type(4), aligned(4)));
typedef float  f2a4   __attribute__((ext_vector_type(2), aligned(4)));

// TN = 1/sqrt(E[tanh(Z)^2]) ~= 1.59253 ; returns TN*tanh(x) = TN - 2*TN/(exp(2x)+1)
__device__ __forceinline__ float tanh_tn(float x) {
    float z = __builtin_amdgcn_exp2f(x * 2.8853900817779268f); // exp(2x)
    float r = __builtin_amdgcn_rcpf(z + 1.0f);
    return 1.59253f - 3.18506f * r;
}

#define P0 136   // LDS pitch (bf16) for W0t [224][128+pad]
#define P1 72    // W1t [64][64+pad]
#define P2 40    // W2t [32][32+pad]

__global__ __launch_bounds__(256, 2)
void lg_kernel(const float* __restrict__ x,  const float* __restrict__ W0g,
               const float* __restrict__ W1g, const float* __restrict__ W2g,
               float* __restrict__ out)
{
    __shared__ __bf16 sW0[224 * P0];  // [n][k], scaled by 1/sqrt(128)
    __shared__ __bf16 sW1[64  * P1];  // [n][k], scaled by 1/8
    __shared__ __bf16 sW2[32  * P2];  // [n][k], scaled by 1/sqrt(32)

    const int tid = threadIdx.x;

    // ---- stage weights: transpose to [n][k], fold scale, cast bf16 ----
    if (tid < 224) {
        const int n = tid;
        #pragma unroll 4
        for (int k0 = 0; k0 < 128; k0 += 8) {
            bf16x8 v;
            #pragma unroll
            for (int u = 0; u < 8; ++u)
                v[u] = (__bf16)(W0g[(k0 + u) * 224 + n] * 0.08838834764831845f);
            *(bf16x8*)&sW0[n * P0 + k0] = v;
        }
    }
    if (tid < 64) {
        const int n = tid;
        #pragma unroll 4
        for (int k0 = 0; k0 < 64; k0 += 8) {
            bf16x8 v;
            #pragma unroll
            for (int u = 0; u < 8; ++u)
                v[u] = (__bf16)(W1g[(k0 + u) * 64 + n] * 0.125f);
            *(bf16x8*)&sW1[n * P1 + k0] = v;
        }
    }
    if (tid < 32) {
        const int n = tid;
        #pragma unroll 4
        for (int k0 = 0; k0 < 32; k0 += 8) {
            bf16x8 v;
            #pragma unroll
            for (int u = 0; u < 8; ++u)
                v[u] = (__bf16)(W2g[(k0 + u) * 32 + n] * 0.17677669529663687f);
            *(bf16x8*)&sW2[n * P2 + k0] = v;
        }
    }
    __syncthreads();

    const int wave = tid >> 6;
    const int lane = tid & 63;
    const int q    = lane >> 4;   // quad: k-group for A/B operands, row-group for D
    const int nn   = lane & 15;   // m for A-operand / n for B-operand & D-col

    const __bf16* w0p = &sW0[nn * P0 + q * 8];
    const __bf16* w1p = &sW1[nn * P1 + q * 8];
    const __bf16* w2p = &sW2[nn * P2 + q * 8];

    #pragma unroll 1
    for (int g = 0; g < 8; ++g) {
        const int rowbase = blockIdx.x * 512 + (g * 4 + wave) * 16;
        const float* xr = x + (size_t)(rowbase + nn) * 480;

        // ---- per-lane global loads: exactly this lane's MFMA A-operand data ----
        // A region: cols kc*32 + q*8 + [0..7]            (x0, K=128)
        // B region: cols 128 + kc*96 + q*24 + [0..23]    (x1: stride-3, all 3 chans)
        // C region: cols 320 + q*40 + [0..39]            (x2: stride-5, all 5 chans)
        f32x4 vA[8], vB[12], vC[10];
        #pragma unroll
        for (int kc = 0; kc < 4; ++kc) {
            vA[kc * 2 + 0] = *(const f4a4*)(xr + kc * 32 + q * 8);
            vA[kc * 2 + 1] = *(const f4a4*)(xr + kc * 32 + q * 8 + 4);
        }
        #pragma unroll
        for (int kc = 0; kc < 2; ++kc) {
            #pragma unroll
            for (int v = 0; v < 6; ++v)
                vB[kc * 6 + v] = *(const f4a4*)(xr + 128 + kc * 96 + q * 24 + v * 4);
        }
        #pragma unroll
        for (int v = 0; v < 10; ++v)
            vC[v] = *(const f4a4*)(xr + 320 + q * 40 + v * 4);

        #define FA(i) (vA[(i) >> 2][(i) & 3])
        #define FB(i) (vB[(i) >> 2][(i) & 3])
        #define FC(i) (vC[(i) >> 2][(i) & 3])

        // ---- A fragments for GEMM A ----
        bf16x8 a0[4];
        #pragma unroll
        for (int kc = 0; kc < 4; ++kc)
            #pragma unroll
            for (int j = 0; j < 8; ++j)
                a0[kc][j] = (__bf16)FA(kc * 8 + j);

        float* outr[4];
        #pragma unroll
        for (int r = 0; r < 4; ++r)
            outr[r] = out + (size_t)(rowbase + q * 4 + r) * 480;

        // ---- GEMM A: y0 = x0@W0*s0 ; scalars stored, gates kept in regs ----
        f32x4 gacc[6];
        #pragma unroll
        for (int nt = 0; nt < 14; ++nt) {
            f32x4 acc = {0.f, 0.f, 0.f, 0.f};
            #pragma unroll
            for (int kc = 0; kc < 4; ++kc) {
                bf16x8 b = *(const bf16x8*)(w0p + nt * 16 * P0 + kc * 32);
                acc = __builtin_amdgcn_mfma_f32_16x16x32_bf16(a0[kc], b, acc, 0, 0, 0);
            }
            f32x4 tv;
            #pragma unroll
            for (int r = 0; r < 4; ++r) tv[r] = tanh_tn(acc[r]);
            if (nt < 8) {
                #pragma unroll
                for (int r = 0; r < 4; ++r)
                    outr[r][nt * 16 + nn] = tv[r];     // scalars, cols 0..127
            } else {
                gacc[nt - 8] = tv;                     // gates, D-layout (matches B/C out)
            }
        }

        // ---- B/C A-fragments: de-interleave stride-3 / stride-5 in registers ----
        bf16x8 aB[3][2];
        #pragma unroll
        for (int c = 0; c < 3; ++c)
            #pragma unroll
            for (int kc = 0; kc < 2; ++kc)
                #pragma unroll
                for (int j = 0; j < 8; ++j)
                    aB[c][kc][j] = (__bf16)FB(kc * 24 + 3 * j + c);
        bf16x8 aC[5];
        #pragma unroll
        for (int c = 0; c < 5; ++c)
            #pragma unroll
            for (int j = 0; j < 8; ++j)
                aC[c][j] = (__bf16)FC(5 * j + c);

        // ---- GEMM B: y1[j,c]*gate[j] -> cols 128 + 3j + c ----
        #pragma unroll
        for (int nt = 0; nt < 4; ++nt) {
            bf16x8 b0 = *(const bf16x8*)(w1p + nt * 16 * P1);
            bf16x8 b1 = *(const bf16x8*)(w1p + nt * 16 * P1 + 32);
            f32x4 acc[3];
            #pragma unroll
            for (int c = 0; c < 3; ++c) {
                f32x4 t = {0.f, 0.f, 0.f, 0.f};
                t = __builtin_amdgcn_mfma_f32_16x16x32_bf16(aB[c][0], b0, t, 0, 0, 0);
                t = __builtin_amdgcn_mfma_f32_16x16x32_bf16(aB[c][1], b1, t, 0, 0, 0);
                acc[c] = t;
            }
            #pragma unroll
            for (int r = 0; r < 4; ++r) {
                float gv = gacc[nt][r];
                int col = 128 + (nt * 16 + nn) * 3;
                f2a4 v01 = { acc[0][r] * gv, acc[1][r] * gv };
                *(f2a4*)(outr[r] + col) = v01;
                outr[r][col + 2] = acc[2][r] * gv;
            }
        }

        // ---- GEMM C: y2[j,c]*gate[64+j] -> cols 320 + 5j + c ----
        #pragma unroll
        for (int nt = 0; nt < 2; ++nt) {
            bf16x8 b = *(const bf16x8*)(w2p + nt * 16 * P2);
            f32x4 acc[5];
            #pragma unroll
            for (int c = 0; c < 5; ++c) {
                f32x4 t = {0.f, 0.f, 0.f, 0.f};
                acc[c] = __builtin_amdgcn_mfma_f32_16x16x32_bf16(aC[c], b, t, 0, 0, 0);
            }
            #pragma unroll
            for (int r = 0; r < 4; ++r) {
                float gv = gacc[4 + nt][r];
                int col = 320 + (nt * 16 + nn) * 5;
                f4a4 v03 = { acc[0][r] * gv, acc[1][r] * gv, acc[2][r] * gv, acc[3][r] * gv };
                *(f4a4*)(outr[r] + col) = v03;
                outr[r][col + 4] = acc[4][r] * gv;
            }
        }
        #undef FA
        #undef FB
        #undef FC
    }
}

extern "C" void kernel_launch(void* const* d_in, const int* in_sizes, int n_in,
                              void* d_out, int out_size, void* d_ws, size_t ws_size,
                              hipStream_t stream) {
    const float* x   = (const float*)d_in[0];
    const float* W0g = (const float*)d_in[1];
    const float* W1g = (const float*)d_in[2];
    const float* W2g = (const float*)d_in[3];
    float* out = (float*)d_out;

    const int n = in_sizes[0] / 480;       // 262144
    const int blocks = n / 512;            // 512 rows per block
    lg_kernel<<<dim3(blocks), dim3(256), 0, stream>>>(x, W0g, W1g, W2g, out);
}